// Round 5
// baseline (324.295 us; speedup 1.0000x reference)
//
#include <hip/hip_runtime.h>
#include <math.h>

#define SQRT3F     1.7320508075688772f
#define SCALE_T    0.17677669529663687f    // 1/sqrt(32)
#define SCALE_M1   0.025515518153991442f   // C_SCALAR/sqrt(32)
#define SCALE_M2   0.014731391274719739f   // C_SCALAR*inv_sqrt3/sqrt(32)
#define SCALE_M34  0.036084391824351615f   // C_SCALAR/4  (== C_VECTOR*inv_sqrt3/sqrt(16))

#define SSTR 36    // LDS stride (floats) for s rows
#define VSTR 52    // LDS stride (floats) for v rows

// quad broadcast of lane TT via DPP (VALU pipe, not DS)
template<int TT>
__device__ __forceinline__ float qb(float x) {
    return __int_as_float(__builtin_amdgcn_update_dpp(
        0, __float_as_int(x), TT * 0x55, 0xF, 0xF, true));
}

__device__ __forceinline__ int lower_bound_src(const int* __restrict__ src, int E, int key)
{
    int lo = 0, hi = E;
    while (lo < hi) {
        int mid = (lo + hi) >> 1;
        if (src[mid] < key) lo = mid + 1; else hi = mid;
    }
    return lo;
}

// ---------------------------------------------------------------------------
// Prep kernel, flat-indexed ranges:
//   [0, Nt*64)            degree-sort permutation (one wave per 64-node tile)
//   [.., +E)              jsh table float4(sh_xyz, bits(j&63))
//   [.., +N+1)            rowptr via binary search
//   [.., +weights)        folded weight matrices T/Ms/Mv
// ---------------------------------------------------------------------------
__global__ void prep_kernel(const float* __restrict__ pos,
                            const int* __restrict__ src, const int* __restrict__ col,
                            int E, int N,
                            const float* __restrict__ emb,
                            const float* __restrict__ W_s2n,
                            const float* __restrict__ W1, const float* __restrict__ W2,
                            const float* __restrict__ W3, const float* __restrict__ W4,
                            const float* __restrict__ Ws, const float* __restrict__ Wv,
                            float4* __restrict__ jsh, int* __restrict__ rowptr,
                            int* __restrict__ perm,
                            float* __restrict__ T, float* __restrict__ Ms,
                            float* __restrict__ Mv)
{
    int idx = blockIdx.x * blockDim.x + threadIdx.x;
    const int NT64 = N;   // N is a multiple of 64 (B graphs x 32 atoms)
    if (idx < NT64) {
        // one wave = one tile of 64 nodes; lane = local node
        int lane = idx & 63;
        int n = idx;                       // global node id (tile*64 + lane)
        int d0 = lower_bound_src(src, E, n);
        int d1 = lower_bound_src(src, E, n + 1);
        int deg = d1 - d0;
        int rank = 0;
        #pragma unroll 8
        for (int k = 0; k < 64; ++k) {
            int dk = __shfl(deg, k, 64);
            rank += (dk > deg) || (dk == deg && k < lane);
        }
        // descending degree: rank 0 = highest degree
        perm[(idx & ~63) + rank] = lane;
        return;
    }
    idx -= NT64;
    if (idx < E) {
        int e = idx;
        int n = src[e], j = col[e];
        float dx = pos[3*n+0] - pos[3*j+0];
        float dy = pos[3*n+1] - pos[3*j+1];
        float dz = pos[3*n+2] - pos[3*j+2];
        float rinv = rsqrtf(dx*dx + dy*dy + dz*dz) * SQRT3F;
        jsh[e] = make_float4(dx*rinv, dy*rinv, dz*rinv, __int_as_float(j & 63));
        return;
    }
    idx -= E;
    if (idx <= N) {
        rowptr[idx] = lower_bound_src(src, E, idx);
        return;
    }
    idx -= (N + 1);
    if (idx < 3200) {
        int r = idx >> 5, c = idx & 31;
        float acc = 0.f;
        for (int k = 0; k < 32; ++k) acc += emb[r*32 + k] * W_s2n[k*32 + c];
        T[idx] = acc * SCALE_T;
    } else if (idx < 3200 + 3*1536) {
        int tix = idx - 3200;
        int l = tix / 1536, rem = tix % 1536;
        int u = rem >> 5, w = rem & 31;
        float acc = 0.f;
        if (u < 32) {
            for (int k = 0; k < 32; ++k)
                acc += W1[l*1024 + u*32 + k] * Ws[l*1024 + k*32 + w];
            acc *= SCALE_M1;
        } else {
            int uu = u - 32;
            for (int k = 0; k < 32; ++k)
                acc += W4[l*512 + uu*32 + k] * Ws[l*1024 + k*32 + w];
            acc *= SCALE_M2;
        }
        Ms[l*1536 + u*32 + w] = acc;
    } else if (idx < 3200 + 3*1536 + 3*768) {
        int tix = idx - 3200 - 3*1536;
        int l = tix / 768, rem = tix % 768;
        int u = rem >> 4, w = rem & 15;
        float acc = 0.f;
        if (u < 32) {
            for (int k = 0; k < 16; ++k)
                acc += W2[l*512 + u*16 + k] * Wv[l*256 + k*16 + w];
        } else {
            int uu = u - 32;
            for (int k = 0; k < 16; ++k)
                acc += W3[l*256 + uu*16 + k] * Wv[l*256 + k*16 + w];
        }
        Mv[l*768 + u*16 + w] = acc * SCALE_M34;
    }
}

// ---------------------------------------------------------------------------
// Phase-2 contribution from quad-lane TT (DPP broadcasts + folded-M FMAs).
// ---------------------------------------------------------------------------
template<int TT>
__device__ __forceinline__ void p2(const float (&a0)[8], const float (&a1)[8][3],
                                   const float (&a2)[4][3], const float (&a3)[4],
                                   const float* __restrict__ Msg,
                                   const float* __restrict__ Mvg,
                                   int t, bool hasv,
                                   float (&po)[8], float (&pv)[12])
{
    #pragma unroll
    for (int k = 0; k < 8; ++k) {
        const int u = 8*TT + k;
        float a  = qb<TT>(a0[k]);
        float bx = qb<TT>(a1[k][0]);
        float by = qb<TT>(a1[k][1]);
        float bz = qb<TT>(a1[k][2]);
        const float4* r = (const float4*)(Msg + u*32 + 8*t);
        float4 rA = r[0], rB = r[1];
        po[0]=fmaf(a,rA.x,po[0]); po[1]=fmaf(a,rA.y,po[1]);
        po[2]=fmaf(a,rA.z,po[2]); po[3]=fmaf(a,rA.w,po[3]);
        po[4]=fmaf(a,rB.x,po[4]); po[5]=fmaf(a,rB.y,po[5]);
        po[6]=fmaf(a,rB.z,po[6]); po[7]=fmaf(a,rB.w,po[7]);
        float4 m = *(const float4*)(Mvg + u*16 + 4*t);
        pv[0]=fmaf(m.x,bx,pv[0]);  pv[1]=fmaf(m.x,by,pv[1]);  pv[2]=fmaf(m.x,bz,pv[2]);
        pv[3]=fmaf(m.y,bx,pv[3]);  pv[4]=fmaf(m.y,by,pv[4]);  pv[5]=fmaf(m.y,bz,pv[5]);
        pv[6]=fmaf(m.z,bx,pv[6]);  pv[7]=fmaf(m.z,by,pv[7]);  pv[8]=fmaf(m.z,bz,pv[8]);
        pv[9]=fmaf(m.w,bx,pv[9]);  pv[10]=fmaf(m.w,by,pv[10]); pv[11]=fmaf(m.w,bz,pv[11]);
    }
    if (hasv) {
        #pragma unroll
        for (int k = 0; k < 4; ++k) {
            const int u = 32 + 4*TT + k;
            float a  = qb<TT>(a3[k]);
            float bx = qb<TT>(a2[k][0]);
            float by = qb<TT>(a2[k][1]);
            float bz = qb<TT>(a2[k][2]);
            const float4* r = (const float4*)(Msg + u*32 + 8*t);
            float4 rA = r[0], rB = r[1];
            po[0]=fmaf(a,rA.x,po[0]); po[1]=fmaf(a,rA.y,po[1]);
            po[2]=fmaf(a,rA.z,po[2]); po[3]=fmaf(a,rA.w,po[3]);
            po[4]=fmaf(a,rB.x,po[4]); po[5]=fmaf(a,rB.y,po[5]);
            po[6]=fmaf(a,rB.z,po[6]); po[7]=fmaf(a,rB.w,po[7]);
            float4 m = *(const float4*)(Mvg + u*16 + 4*t);
            pv[0]=fmaf(m.x,bx,pv[0]);  pv[1]=fmaf(m.x,by,pv[1]);  pv[2]=fmaf(m.x,bz,pv[2]);
            pv[3]=fmaf(m.y,bx,pv[3]);  pv[4]=fmaf(m.y,by,pv[4]);  pv[5]=fmaf(m.y,bz,pv[5]);
            pv[6]=fmaf(m.z,bx,pv[6]);  pv[7]=fmaf(m.z,by,pv[7]);  pv[8]=fmaf(m.z,bz,pv[8]);
            pv[9]=fmaf(m.w,bx,pv[9]);  pv[10]=fmaf(m.w,by,pv[10]); pv[11]=fmaf(m.w,bz,pv[11]);
        }
    }
}

// ---------------------------------------------------------------------------
// Fused GNN: one block = 2 graphs (64 nodes, 256 threads, 4 lanes/node).
// s,v live in LDS across all 3 layers. Edge table read from global (fp32,
// L2-resident after layer 1). Quads are assigned nodes in degree-sorted
// order (perm) so each wave's loop trip count ~= its degree quantile.
// LDS ~22.8 KB -> 6 blocks/CU (24 waves).
// ---------------------------------------------------------------------------
__global__ __launch_bounds__(256, 6)
void gnn_kernel(const float* __restrict__ T, const int* __restrict__ z,
                const int* __restrict__ rowptr, const int* __restrict__ perm,
                const float4* __restrict__ jsh,
                const float* __restrict__ Ms, const float* __restrict__ Mv,
                float* __restrict__ hg, int N)
{
    __shared__ __align__(16) float sS[64*SSTR];
    __shared__ __align__(16) float sV[64*VSTR];
    __shared__ int rp[65];

    const int base = blockIdx.x * 64;
    const int tid = threadIdx.x;

    if (tid < 65) rp[tid] = rowptr[base + tid];
    for (int i = tid; i < 64*VSTR; i += 256) sV[i] = 0.f;
    for (int i = tid; i < 2048; i += 256) {
        int n = i >> 5, c = i & 31;
        sS[n*SSTR + c] = T[z[base + n]*32 + c];
    }
    const int pl = perm[base + (tid >> 2)];   // my node (local 0..63), degree-sorted
    const int t  = tid & 3;                   // quad lane: s-ch 8t.., v-ch 4t..
    __syncthreads();

    const int el0 = rp[pl], el1 = rp[pl + 1];  // global edge range

    for (int lay = 0; lay < 3; ++lay) {
        const bool hasv = (lay != 0);
        const float* Msg = Ms + lay*1536;
        const float* Mvg = Mv + lay*768;

        float a0[8]    = {};
        float a1[8][3] = {};
        float a2[4][3] = {};
        float a3[4]    = {};

        float4 jsp = (el0 < el1) ? jsh[el0] : make_float4(0.f,0.f,0.f,0.f);
        if (!hasv) {
            for (int e = el0; e < el1; ++e) {
                float4 js = jsp;
                if (e + 1 < el1) jsp = jsh[e + 1];
                int jl = __float_as_int(js.w);
                const float* Sj = sS + jl*SSTR + 8*t;
                float4 sA = *(const float4*)Sj;
                float4 sB = *(const float4*)(Sj + 4);
                float ssv[8] = {sA.x,sA.y,sA.z,sA.w,sB.x,sB.y,sB.z,sB.w};
                #pragma unroll
                for (int k = 0; k < 8; ++k) {
                    a0[k] += ssv[k];
                    a1[k][0] = fmaf(ssv[k], js.x, a1[k][0]);
                    a1[k][1] = fmaf(ssv[k], js.y, a1[k][1]);
                    a1[k][2] = fmaf(ssv[k], js.z, a1[k][2]);
                }
            }
        } else {
            for (int e = el0; e < el1; ++e) {
                float4 js = jsp;
                if (e + 1 < el1) jsp = jsh[e + 1];
                int jl = __float_as_int(js.w);
                const float* Sj = sS + jl*SSTR + 8*t;
                const float* Vj = sV + jl*VSTR + 12*t;
                float4 sA = *(const float4*)Sj;
                float4 sB = *(const float4*)(Sj + 4);
                float4 vA = *(const float4*)Vj;
                float4 vB = *(const float4*)(Vj + 4);
                float4 vC = *(const float4*)(Vj + 8);
                float ssv[8] = {sA.x,sA.y,sA.z,sA.w,sB.x,sB.y,sB.z,sB.w};
                #pragma unroll
                for (int k = 0; k < 8; ++k) {
                    a0[k] += ssv[k];
                    a1[k][0] = fmaf(ssv[k], js.x, a1[k][0]);
                    a1[k][1] = fmaf(ssv[k], js.y, a1[k][1]);
                    a1[k][2] = fmaf(ssv[k], js.z, a1[k][2]);
                }
                float vv[4][3] = {{vA.x,vA.y,vA.z},{vA.w,vB.x,vB.y},
                                  {vB.z,vB.w,vC.x},{vC.y,vC.z,vC.w}};
                #pragma unroll
                for (int k = 0; k < 4; ++k) {
                    a2[k][0] += vv[k][0]; a2[k][1] += vv[k][1]; a2[k][2] += vv[k][2];
                    a3[k] = fmaf(vv[k][0], js.x,
                            fmaf(vv[k][1], js.y, fmaf(vv[k][2], js.z, a3[k])));
                }
            }
        }
        __syncthreads();   // all gathers done before in-place update

        float po[8]  = {};
        float pv[12] = {};
        p2<0>(a0, a1, a2, a3, Msg, Mvg, t, hasv, po, pv);
        p2<1>(a0, a1, a2, a3, Msg, Mvg, t, hasv, po, pv);
        p2<2>(a0, a1, a2, a3, Msg, Mvg, t, hasv, po, pv);
        p2<3>(a0, a1, a2, a3, Msg, Mvg, t, hasv, po, pv);

        // residual + relu, in-place (lane-owned slices of node pl)
        float* Sp = sS + pl*SSTR + 8*t;
        float4 s0 = *(float4*)Sp, s1 = *(float4*)(Sp + 4);
        s0.x += fmaxf(po[0],0.f); s0.y += fmaxf(po[1],0.f);
        s0.z += fmaxf(po[2],0.f); s0.w += fmaxf(po[3],0.f);
        s1.x += fmaxf(po[4],0.f); s1.y += fmaxf(po[5],0.f);
        s1.z += fmaxf(po[6],0.f); s1.w += fmaxf(po[7],0.f);
        *(float4*)Sp = s0; *(float4*)(Sp + 4) = s1;

        float* Vp = sV + pl*VSTR + 12*t;
        float4 v0 = *(float4*)Vp, v1 = *(float4*)(Vp + 4), v2 = *(float4*)(Vp + 8);
        v0.x += fmaxf(pv[0],0.f);  v0.y += fmaxf(pv[1],0.f);
        v0.z += fmaxf(pv[2],0.f);  v0.w += fmaxf(pv[3],0.f);
        v1.x += fmaxf(pv[4],0.f);  v1.y += fmaxf(pv[5],0.f);
        v1.z += fmaxf(pv[6],0.f);  v1.w += fmaxf(pv[7],0.f);
        v2.x += fmaxf(pv[8],0.f);  v2.y += fmaxf(pv[9],0.f);
        v2.z += fmaxf(pv[10],0.f); v2.w += fmaxf(pv[11],0.f);
        *(float4*)Vp = v0; *(float4*)(Vp + 4) = v1; *(float4*)(Vp + 8) = v2;

        __syncthreads();
    }

    // fused sum-pool: 2 graphs x 80 features
    if (tid < 160) {
        int g = tid / 80, f = tid - g*80;
        float acc = 0.f;
        if (f < 32) {
            for (int k = 0; k < 32; ++k) acc += sS[(g*32 + k)*SSTR + f];
        } else {
            int c = f - 32;
            for (int k = 0; k < 32; ++k) acc += sV[(g*32 + k)*VSTR + c];
        }
        hg[(size_t)(blockIdx.x*2 + g)*80 + f] = acc;
    }
}

// ---------------------------------------------------------------------------
// MLP head: 4 graphs per block; Wr1/Wr2 shared; split-K stage 2.
// ---------------------------------------------------------------------------
__launch_bounds__(256)
__global__ void mlp_kernel(const float* __restrict__ hg,
                           const float* __restrict__ Wr1, const float* __restrict__ br1,
                           const float* __restrict__ Wr2, const float* __restrict__ br2,
                           float* __restrict__ out, int B)
{
    __shared__ __align__(16) float h1[4][256];
    __shared__ float red[4][128];
    const int g0 = blockIdx.x * 4;
    const int w = threadIdx.x;

    float acc0 = br1[w];
    float acc1 = acc0, acc2 = acc0, acc3 = acc0;
    #pragma unroll 4
    for (int f = 0; f < 80; ++f) {
        float wv = Wr1[f*256 + w];
        acc0 = fmaf(hg[(size_t)(g0+0)*80 + f], wv, acc0);
        acc1 = fmaf(hg[(size_t)(g0+1)*80 + f], wv, acc1);
        acc2 = fmaf(hg[(size_t)(g0+2)*80 + f], wv, acc2);
        acc3 = fmaf(hg[(size_t)(g0+3)*80 + f], wv, acc3);
    }
    h1[0][w] = fmaxf(acc0, 0.f);
    h1[1][w] = fmaxf(acc1, 0.f);
    h1[2][w] = fmaxf(acc2, 0.f);
    h1[3][w] = fmaxf(acc3, 0.f);
    __syncthreads();

    const int w2 = threadIdx.x & 127, kh = threadIdx.x >> 7;
    const float4* h1v = (const float4*)(&h1[0][0]);   // [4][64] float4 view
    float s0 = 0.f, s1 = 0.f, s2 = 0.f, s3 = 0.f;
    #pragma unroll 2
    for (int k4 = kh*32; k4 < kh*32 + 32; ++k4) {
        float4 hA = h1v[0*64 + k4];
        float4 hB = h1v[1*64 + k4];
        float4 hC = h1v[2*64 + k4];
        float4 hD = h1v[3*64 + k4];
        int k = k4 * 4;
        float m0 = Wr2[(size_t)(k+0)*128 + w2];
        float m1 = Wr2[(size_t)(k+1)*128 + w2];
        float m2 = Wr2[(size_t)(k+2)*128 + w2];
        float m3 = Wr2[(size_t)(k+3)*128 + w2];
        s0 = fmaf(hA.x,m0, fmaf(hA.y,m1, fmaf(hA.z,m2, fmaf(hA.w,m3, s0))));
        s1 = fmaf(hB.x,m0, fmaf(hB.y,m1, fmaf(hB.z,m2, fmaf(hB.w,m3, s1))));
        s2 = fmaf(hC.x,m0, fmaf(hC.y,m1, fmaf(hC.z,m2, fmaf(hC.w,m3, s2))));
        s3 = fmaf(hD.x,m0, fmaf(hD.y,m1, fmaf(hD.z,m2, fmaf(hD.w,m3, s3))));
    }
    if (kh) {
        red[0][w2] = s0; red[1][w2] = s1; red[2][w2] = s2; red[3][w2] = s3;
    }
    __syncthreads();
    if (!kh) {
        float b = br2[w2];
        out[(size_t)(g0+0)*128 + w2] = s0 + red[0][w2] + b;
        out[(size_t)(g0+1)*128 + w2] = s1 + red[1][w2] + b;
        out[(size_t)(g0+2)*128 + w2] = s2 + red[2][w2] + b;
        out[(size_t)(g0+3)*128 + w2] = s3 + red[3][w2] + b;
    }
}

// ---------------------------------------------------------------------------
extern "C" void kernel_launch(void* const* d_in, const int* in_sizes, int n_in,
                              void* d_out, int out_size, void* d_ws, size_t ws_size,
                              hipStream_t stream)
{
    const float* pos   = (const float*)d_in[0];
    const int*   z     = (const int*)d_in[1];
    const int*   eidx  = (const int*)d_in[3];
    const float* emb   = (const float*)d_in[5];
    const float* W_s2n = (const float*)d_in[6];
    const float* W1    = (const float*)d_in[7];
    const float* W2    = (const float*)d_in[8];
    const float* W3    = (const float*)d_in[9];
    const float* W4    = (const float*)d_in[10];
    const float* Ws    = (const float*)d_in[11];
    const float* Wv    = (const float*)d_in[12];
    const float* Wr1   = (const float*)d_in[13];
    const float* br1   = (const float*)d_in[14];
    const float* Wr2   = (const float*)d_in[15];
    const float* br2   = (const float*)d_in[16];
    float* out = (float*)d_out;

    const int N = in_sizes[0] / 3;
    const int E = in_sizes[3] / 2;
    const int B = out_size / 128;

    const int* src = eidx;
    const int* col = eidx + E;

    // workspace layout (16B-aligned chunks)
    char* p = (char*)d_ws;
    float4* jsh = (float4*)p;  p += (size_t)E * 16;
    float* T  = (float*)p;     p += 3200 * 4;
    float* Ms = (float*)p;     p += 3 * 1536 * 4;
    float* Mv = (float*)p;     p += 3 * 768 * 4;
    int* rowptr = (int*)p;     p += (((size_t)(N + 1) * 4 + 15) & ~(size_t)15);
    int* perm = (int*)p;       p += (size_t)N * 4;
    float* hg = (float*)p;     p += (size_t)B * 80 * 4;

    const int prep_total = N + E + (N + 1) + 3200 + 3*1536 + 3*768;
    prep_kernel<<<(prep_total + 255) / 256, 256, 0, stream>>>(
        pos, src, col, E, N, emb, W_s2n, W1, W2, W3, W4, Ws, Wv,
        jsh, rowptr, perm, T, Ms, Mv);

    gnn_kernel<<<(N + 63) / 64, 256, 0, stream>>>(T, z, rowptr, perm, jsh, Ms, Mv, hg, N);

    mlp_kernel<<<B / 4, 256, 0, stream>>>(hg, Wr1, br1, Wr2, br2, out, B);
}

// Round 6
// 204.883 us; speedup vs baseline: 1.5828x; 1.5828x over previous
//
#include <hip/hip_runtime.h>
#include <math.h>

#define SQRT3F     1.7320508075688772f
#define SCALE_T    0.17677669529663687f    // 1/sqrt(32)
#define SCALE_M1   0.025515518153991442f   // C_SCALAR/sqrt(32)
#define SCALE_M2   0.014731391274719739f   // C_SCALAR*inv_sqrt3/sqrt(32)
#define SCALE_M34  0.036084391824351615f   // C_SCALAR/4  (== C_VECTOR*inv_sqrt3/sqrt(16))

#define SSTR 36    // LDS stride (floats) for s rows
#define VSTR 52    // LDS stride (floats) for v rows

// quad broadcast of lane TT via DPP (VALU pipe, not DS)
template<int TT>
__device__ __forceinline__ float qb(float x) {
    return __int_as_float(__builtin_amdgcn_update_dpp(
        0, __float_as_int(x), TT * 0x55, 0xF, 0xF, true));
}

__device__ __forceinline__ int lower_bound_src(const int* __restrict__ src, int E, int key)
{
    int lo = 0, hi = E;
    while (lo < hi) {
        int mid = (lo + hi) >> 1;
        if (src[mid] < key) lo = mid + 1; else hi = mid;
    }
    return lo;
}

// ---------------------------------------------------------------------------
// Prep kernel, flat-indexed ranges:
//   [0, N)                degree-sort permutation (one wave per 64-node tile)
//   [.., +E)              jsh table float4(sh_xyz, bits(j&63))
//   [.., +N+1)            rowptr via binary search
//   [.., +weights)        folded weight matrices T/Ms/Mv
// ---------------------------------------------------------------------------
__global__ void prep_kernel(const float* __restrict__ pos,
                            const int* __restrict__ src, const int* __restrict__ col,
                            int E, int N,
                            const float* __restrict__ emb,
                            const float* __restrict__ W_s2n,
                            const float* __restrict__ W1, const float* __restrict__ W2,
                            const float* __restrict__ W3, const float* __restrict__ W4,
                            const float* __restrict__ Ws, const float* __restrict__ Wv,
                            float4* __restrict__ jsh, int* __restrict__ rowptr,
                            int* __restrict__ perm,
                            float* __restrict__ T, float* __restrict__ Ms,
                            float* __restrict__ Mv)
{
    int idx = blockIdx.x * blockDim.x + threadIdx.x;
    if (idx < N) {
        // one wave = one tile of 64 nodes; lane = local node
        int lane = idx & 63;
        int n = idx;
        int d0 = lower_bound_src(src, E, n);
        int d1 = lower_bound_src(src, E, n + 1);
        int deg = d1 - d0;
        int rank = 0;
        #pragma unroll 8
        for (int k = 0; k < 64; ++k) {
            int dk = __shfl(deg, k, 64);
            rank += (dk > deg) || (dk == deg && k < lane);
        }
        // descending degree: rank 0 = highest degree
        perm[(idx & ~63) + rank] = lane;
        return;
    }
    idx -= N;
    if (idx < E) {
        int e = idx;
        int n = src[e], j = col[e];
        float dx = pos[3*n+0] - pos[3*j+0];
        float dy = pos[3*n+1] - pos[3*j+1];
        float dz = pos[3*n+2] - pos[3*j+2];
        float rinv = rsqrtf(dx*dx + dy*dy + dz*dz) * SQRT3F;
        jsh[e] = make_float4(dx*rinv, dy*rinv, dz*rinv, __int_as_float(j & 63));
        return;
    }
    idx -= E;
    if (idx <= N) {
        rowptr[idx] = lower_bound_src(src, E, idx);
        return;
    }
    idx -= (N + 1);
    if (idx < 3200) {
        int r = idx >> 5, c = idx & 31;
        float acc = 0.f;
        for (int k = 0; k < 32; ++k) acc += emb[r*32 + k] * W_s2n[k*32 + c];
        T[idx] = acc * SCALE_T;
    } else if (idx < 3200 + 3*1536) {
        int tix = idx - 3200;
        int l = tix / 1536, rem = tix % 1536;
        int u = rem >> 5, w = rem & 31;
        float acc = 0.f;
        if (u < 32) {
            for (int k = 0; k < 32; ++k)
                acc += W1[l*1024 + u*32 + k] * Ws[l*1024 + k*32 + w];
            acc *= SCALE_M1;
        } else {
            int uu = u - 32;
            for (int k = 0; k < 32; ++k)
                acc += W4[l*512 + uu*32 + k] * Ws[l*1024 + k*32 + w];
            acc *= SCALE_M2;
        }
        Ms[l*1536 + u*32 + w] = acc;
    } else if (idx < 3200 + 3*1536 + 3*768) {
        int tix = idx - 3200 - 3*1536;
        int l = tix / 768, rem = tix % 768;
        int u = rem >> 4, w = rem & 15;
        float acc = 0.f;
        if (u < 32) {
            for (int k = 0; k < 16; ++k)
                acc += W2[l*512 + u*16 + k] * Wv[l*256 + k*16 + w];
        } else {
            int uu = u - 32;
            for (int k = 0; k < 16; ++k)
                acc += W3[l*256 + uu*16 + k] * Wv[l*256 + k*16 + w];
        }
        Mv[l*768 + u*16 + w] = acc * SCALE_M34;
    }
}

// ---------------------------------------------------------------------------
// Phase-2 contribution from quad-lane TT (DPP broadcasts + folded-M FMAs).
// ---------------------------------------------------------------------------
template<int TT>
__device__ __forceinline__ void p2(const float (&a0)[8], const float (&a1)[8][3],
                                   const float (&a2)[4][3], const float (&a3)[4],
                                   const float* __restrict__ Msg,
                                   const float* __restrict__ Mvg,
                                   int t, bool hasv,
                                   float (&po)[8], float (&pv)[12])
{
    #pragma unroll
    for (int k = 0; k < 8; ++k) {
        const int u = 8*TT + k;
        float a  = qb<TT>(a0[k]);
        float bx = qb<TT>(a1[k][0]);
        float by = qb<TT>(a1[k][1]);
        float bz = qb<TT>(a1[k][2]);
        const float4* r = (const float4*)(Msg + u*32 + 8*t);
        float4 rA = r[0], rB = r[1];
        po[0]=fmaf(a,rA.x,po[0]); po[1]=fmaf(a,rA.y,po[1]);
        po[2]=fmaf(a,rA.z,po[2]); po[3]=fmaf(a,rA.w,po[3]);
        po[4]=fmaf(a,rB.x,po[4]); po[5]=fmaf(a,rB.y,po[5]);
        po[6]=fmaf(a,rB.z,po[6]); po[7]=fmaf(a,rB.w,po[7]);
        float4 m = *(const float4*)(Mvg + u*16 + 4*t);
        pv[0]=fmaf(m.x,bx,pv[0]);  pv[1]=fmaf(m.x,by,pv[1]);  pv[2]=fmaf(m.x,bz,pv[2]);
        pv[3]=fmaf(m.y,bx,pv[3]);  pv[4]=fmaf(m.y,by,pv[4]);  pv[5]=fmaf(m.y,bz,pv[5]);
        pv[6]=fmaf(m.z,bx,pv[6]);  pv[7]=fmaf(m.z,by,pv[7]);  pv[8]=fmaf(m.z,bz,pv[8]);
        pv[9]=fmaf(m.w,bx,pv[9]);  pv[10]=fmaf(m.w,by,pv[10]); pv[11]=fmaf(m.w,bz,pv[11]);
    }
    if (hasv) {
        #pragma unroll
        for (int k = 0; k < 4; ++k) {
            const int u = 32 + 4*TT + k;
            float a  = qb<TT>(a3[k]);
            float bx = qb<TT>(a2[k][0]);
            float by = qb<TT>(a2[k][1]);
            float bz = qb<TT>(a2[k][2]);
            const float4* r = (const float4*)(Msg + u*32 + 8*t);
            float4 rA = r[0], rB = r[1];
            po[0]=fmaf(a,rA.x,po[0]); po[1]=fmaf(a,rA.y,po[1]);
            po[2]=fmaf(a,rA.z,po[2]); po[3]=fmaf(a,rA.w,po[3]);
            po[4]=fmaf(a,rB.x,po[4]); po[5]=fmaf(a,rB.y,po[5]);
            po[6]=fmaf(a,rB.z,po[6]); po[7]=fmaf(a,rB.w,po[7]);
            float4 m = *(const float4*)(Mvg + u*16 + 4*t);
            pv[0]=fmaf(m.x,bx,pv[0]);  pv[1]=fmaf(m.x,by,pv[1]);  pv[2]=fmaf(m.x,bz,pv[2]);
            pv[3]=fmaf(m.y,bx,pv[3]);  pv[4]=fmaf(m.y,by,pv[4]);  pv[5]=fmaf(m.y,bz,pv[5]);
            pv[6]=fmaf(m.z,bx,pv[6]);  pv[7]=fmaf(m.z,by,pv[7]);  pv[8]=fmaf(m.z,bz,pv[8]);
            pv[9]=fmaf(m.w,bx,pv[9]);  pv[10]=fmaf(m.w,by,pv[10]); pv[11]=fmaf(m.w,bz,pv[11]);
        }
    }
}

// ---------------------------------------------------------------------------
// Fused GNN: one block = 2 graphs (64 nodes, 256 threads, 4 lanes/node).
// s,v live in LDS across all 3 layers. Edge table read from global (fp32,
// L2-resident after layer 1). Quads own nodes in degree-sorted order (perm).
// LDS ~22.8 KB -> 7 blocks/CU by LDS; VGPR 64 -> 8 waves/SIMD.
// NOTE: min-waves bound MUST stay at 4 — (256,6) forces 40 VGPRs and spills
// the 48 accumulators to scratch (round-5: 500 MB HBM spill traffic, 2.3x slower).
// ---------------------------------------------------------------------------
__global__ __launch_bounds__(256, 4)
void gnn_kernel(const float* __restrict__ T, const int* __restrict__ z,
                const int* __restrict__ rowptr, const int* __restrict__ perm,
                const float4* __restrict__ jsh,
                const float* __restrict__ Ms, const float* __restrict__ Mv,
                float* __restrict__ hg, int N)
{
    __shared__ __align__(16) float sS[64*SSTR];
    __shared__ __align__(16) float sV[64*VSTR];
    __shared__ int rp[65];

    const int base = blockIdx.x * 64;
    const int tid = threadIdx.x;

    if (tid < 65) rp[tid] = rowptr[base + tid];
    for (int i = tid; i < 64*VSTR; i += 256) sV[i] = 0.f;
    for (int i = tid; i < 2048; i += 256) {
        int n = i >> 5, c = i & 31;
        sS[n*SSTR + c] = T[z[base + n]*32 + c];
    }
    const int pl = perm[base + (tid >> 2)];   // my node (local 0..63), degree-sorted
    const int t  = tid & 3;                   // quad lane: s-ch 8t.., v-ch 4t..
    __syncthreads();

    const int el0 = rp[pl], el1 = rp[pl + 1];  // global edge range

    for (int lay = 0; lay < 3; ++lay) {
        const bool hasv = (lay != 0);
        const float* Msg = Ms + lay*1536;
        const float* Mvg = Mv + lay*768;

        float a0[8]    = {};
        float a1[8][3] = {};
        float a2[4][3] = {};
        float a3[4]    = {};

        float4 jsp = (el0 < el1) ? jsh[el0] : make_float4(0.f,0.f,0.f,0.f);
        if (!hasv) {
            for (int e = el0; e < el1; ++e) {
                float4 js = jsp;
                if (e + 1 < el1) jsp = jsh[e + 1];
                int jl = __float_as_int(js.w);
                const float* Sj = sS + jl*SSTR + 8*t;
                float4 sA = *(const float4*)Sj;
                float4 sB = *(const float4*)(Sj + 4);
                float ssv[8] = {sA.x,sA.y,sA.z,sA.w,sB.x,sB.y,sB.z,sB.w};
                #pragma unroll
                for (int k = 0; k < 8; ++k) {
                    a0[k] += ssv[k];
                    a1[k][0] = fmaf(ssv[k], js.x, a1[k][0]);
                    a1[k][1] = fmaf(ssv[k], js.y, a1[k][1]);
                    a1[k][2] = fmaf(ssv[k], js.z, a1[k][2]);
                }
            }
        } else {
            for (int e = el0; e < el1; ++e) {
                float4 js = jsp;
                if (e + 1 < el1) jsp = jsh[e + 1];
                int jl = __float_as_int(js.w);
                const float* Sj = sS + jl*SSTR + 8*t;
                const float* Vj = sV + jl*VSTR + 12*t;
                float4 sA = *(const float4*)Sj;
                float4 sB = *(const float4*)(Sj + 4);
                float4 vA = *(const float4*)Vj;
                float4 vB = *(const float4*)(Vj + 4);
                float4 vC = *(const float4*)(Vj + 8);
                float ssv[8] = {sA.x,sA.y,sA.z,sA.w,sB.x,sB.y,sB.z,sB.w};
                #pragma unroll
                for (int k = 0; k < 8; ++k) {
                    a0[k] += ssv[k];
                    a1[k][0] = fmaf(ssv[k], js.x, a1[k][0]);
                    a1[k][1] = fmaf(ssv[k], js.y, a1[k][1]);
                    a1[k][2] = fmaf(ssv[k], js.z, a1[k][2]);
                }
                float vv[4][3] = {{vA.x,vA.y,vA.z},{vA.w,vB.x,vB.y},
                                  {vB.z,vB.w,vC.x},{vC.y,vC.z,vC.w}};
                #pragma unroll
                for (int k = 0; k < 4; ++k) {
                    a2[k][0] += vv[k][0]; a2[k][1] += vv[k][1]; a2[k][2] += vv[k][2];
                    a3[k] = fmaf(vv[k][0], js.x,
                            fmaf(vv[k][1], js.y, fmaf(vv[k][2], js.z, a3[k])));
                }
            }
        }
        __syncthreads();   // all gathers done before in-place update

        float po[8]  = {};
        float pv[12] = {};
        p2<0>(a0, a1, a2, a3, Msg, Mvg, t, hasv, po, pv);
        p2<1>(a0, a1, a2, a3, Msg, Mvg, t, hasv, po, pv);
        p2<2>(a0, a1, a2, a3, Msg, Mvg, t, hasv, po, pv);
        p2<3>(a0, a1, a2, a3, Msg, Mvg, t, hasv, po, pv);

        // residual + relu, in-place (lane-owned slices of node pl)
        float* Sp = sS + pl*SSTR + 8*t;
        float4 s0 = *(float4*)Sp, s1 = *(float4*)(Sp + 4);
        s0.x += fmaxf(po[0],0.f); s0.y += fmaxf(po[1],0.f);
        s0.z += fmaxf(po[2],0.f); s0.w += fmaxf(po[3],0.f);
        s1.x += fmaxf(po[4],0.f); s1.y += fmaxf(po[5],0.f);
        s1.z += fmaxf(po[6],0.f); s1.w += fmaxf(po[7],0.f);
        *(float4*)Sp = s0; *(float4*)(Sp + 4) = s1;

        float* Vp = sV + pl*VSTR + 12*t;
        float4 v0 = *(float4*)Vp, v1 = *(float4*)(Vp + 4), v2 = *(float4*)(Vp + 8);
        v0.x += fmaxf(pv[0],0.f);  v0.y += fmaxf(pv[1],0.f);
        v0.z += fmaxf(pv[2],0.f);  v0.w += fmaxf(pv[3],0.f);
        v1.x += fmaxf(pv[4],0.f);  v1.y += fmaxf(pv[5],0.f);
        v1.z += fmaxf(pv[6],0.f);  v1.w += fmaxf(pv[7],0.f);
        v2.x += fmaxf(pv[8],0.f);  v2.y += fmaxf(pv[9],0.f);
        v2.z += fmaxf(pv[10],0.f); v2.w += fmaxf(pv[11],0.f);
        *(float4*)Vp = v0; *(float4*)(Vp + 4) = v1; *(float4*)(Vp + 8) = v2;

        __syncthreads();
    }

    // fused sum-pool: 2 graphs x 80 features
    if (tid < 160) {
        int g = tid / 80, f = tid - g*80;
        float acc = 0.f;
        if (f < 32) {
            for (int k = 0; k < 32; ++k) acc += sS[(g*32 + k)*SSTR + f];
        } else {
            int c = f - 32;
            for (int k = 0; k < 32; ++k) acc += sV[(g*32 + k)*VSTR + c];
        }
        hg[(size_t)(blockIdx.x*2 + g)*80 + f] = acc;
    }
}

// ---------------------------------------------------------------------------
// MLP head: 4 graphs per block; Wr1/Wr2 shared; split-K stage 2.
// ---------------------------------------------------------------------------
__launch_bounds__(256)
__global__ void mlp_kernel(const float* __restrict__ hg,
                           const float* __restrict__ Wr1, const float* __restrict__ br1,
                           const float* __restrict__ Wr2, const float* __restrict__ br2,
                           float* __restrict__ out, int B)
{
    __shared__ __align__(16) float h1[4][256];
    __shared__ float red[4][128];
    const int g0 = blockIdx.x * 4;
    const int w = threadIdx.x;

    float acc0 = br1[w];
    float acc1 = acc0, acc2 = acc0, acc3 = acc0;
    #pragma unroll 4
    for (int f = 0; f < 80; ++f) {
        float wv = Wr1[f*256 + w];
        acc0 = fmaf(hg[(size_t)(g0+0)*80 + f], wv, acc0);
        acc1 = fmaf(hg[(size_t)(g0+1)*80 + f], wv, acc1);
        acc2 = fmaf(hg[(size_t)(g0+2)*80 + f], wv, acc2);
        acc3 = fmaf(hg[(size_t)(g0+3)*80 + f], wv, acc3);
    }
    h1[0][w] = fmaxf(acc0, 0.f);
    h1[1][w] = fmaxf(acc1, 0.f);
    h1[2][w] = fmaxf(acc2, 0.f);
    h1[3][w] = fmaxf(acc3, 0.f);
    __syncthreads();

    const int w2 = threadIdx.x & 127, kh = threadIdx.x >> 7;
    const float4* h1v = (const float4*)(&h1[0][0]);   // [4][64] float4 view
    float s0 = 0.f, s1 = 0.f, s2 = 0.f, s3 = 0.f;
    #pragma unroll 2
    for (int k4 = kh*32; k4 < kh*32 + 32; ++k4) {
        float4 hA = h1v[0*64 + k4];
        float4 hB = h1v[1*64 + k4];
        float4 hC = h1v[2*64 + k4];
        float4 hD = h1v[3*64 + k4];
        int k = k4 * 4;
        float m0 = Wr2[(size_t)(k+0)*128 + w2];
        float m1 = Wr2[(size_t)(k+1)*128 + w2];
        float m2 = Wr2[(size_t)(k+2)*128 + w2];
        float m3 = Wr2[(size_t)(k+3)*128 + w2];
        s0 = fmaf(hA.x,m0, fmaf(hA.y,m1, fmaf(hA.z,m2, fmaf(hA.w,m3, s0))));
        s1 = fmaf(hB.x,m0, fmaf(hB.y,m1, fmaf(hB.z,m2, fmaf(hB.w,m3, s1))));
        s2 = fmaf(hC.x,m0, fmaf(hC.y,m1, fmaf(hC.z,m2, fmaf(hC.w,m3, s2))));
        s3 = fmaf(hD.x,m0, fmaf(hD.y,m1, fmaf(hD.z,m2, fmaf(hD.w,m3, s3))));
    }
    if (kh) {
        red[0][w2] = s0; red[1][w2] = s1; red[2][w2] = s2; red[3][w2] = s3;
    }
    __syncthreads();
    if (!kh) {
        float b = br2[w2];
        out[(size_t)(g0+0)*128 + w2] = s0 + red[0][w2] + b;
        out[(size_t)(g0+1)*128 + w2] = s1 + red[1][w2] + b;
        out[(size_t)(g0+2)*128 + w2] = s2 + red[2][w2] + b;
        out[(size_t)(g0+3)*128 + w2] = s3 + red[3][w2] + b;
    }
}

// ---------------------------------------------------------------------------
extern "C" void kernel_launch(void* const* d_in, const int* in_sizes, int n_in,
                              void* d_out, int out_size, void* d_ws, size_t ws_size,
                              hipStream_t stream)
{
    const float* pos   = (const float*)d_in[0];
    const int*   z     = (const int*)d_in[1];
    const int*   eidx  = (const int*)d_in[3];
    const float* emb   = (const float*)d_in[5];
    const float* W_s2n = (const float*)d_in[6];
    const float* W1    = (const float*)d_in[7];
    const float* W2    = (const float*)d_in[8];
    const float* W3    = (const float*)d_in[9];
    const float* W4    = (const float*)d_in[10];
    const float* Ws    = (const float*)d_in[11];
    const float* Wv    = (const float*)d_in[12];
    const float* Wr1   = (const float*)d_in[13];
    const float* br1   = (const float*)d_in[14];
    const float* Wr2   = (const float*)d_in[15];
    const float* br2   = (const float*)d_in[16];
    float* out = (float*)d_out;

    const int N = in_sizes[0] / 3;
    const int E = in_sizes[3] / 2;
    const int B = out_size / 128;

    const int* src = eidx;
    const int* col = eidx + E;

    // workspace layout (16B-aligned chunks)
    char* p = (char*)d_ws;
    float4* jsh = (float4*)p;  p += (size_t)E * 16;
    float* T  = (float*)p;     p += 3200 * 4;
    float* Ms = (float*)p;     p += 3 * 1536 * 4;
    float* Mv = (float*)p;     p += 3 * 768 * 4;
    int* rowptr = (int*)p;     p += (((size_t)(N + 1) * 4 + 15) & ~(size_t)15);
    int* perm = (int*)p;       p += (size_t)N * 4;
    float* hg = (float*)p;     p += (size_t)B * 80 * 4;

    const int prep_total = N + E + (N + 1) + 3200 + 3*1536 + 3*768;
    prep_kernel<<<(prep_total + 255) / 256, 256, 0, stream>>>(
        pos, src, col, E, N, emb, W_s2n, W1, W2, W3, W4, Ws, Wv,
        jsh, rowptr, perm, T, Ms, Mv);

    gnn_kernel<<<(N + 63) / 64, 256, 0, stream>>>(T, z, rowptr, perm, jsh, Ms, Mv, hg, N);

    mlp_kernel<<<B / 4, 256, 0, stream>>>(hg, Wr1, br1, Wr2, br2, out, B);
}